// Round 1
// baseline (691.032 us; speedup 1.0000x reference)
//
#include <hip/hip_runtime.h>
#include <hip/hip_bf16.h>
#include <stdint.h>

// Problem constants (B=32, D=256, H=32, W=32, K=2048)
#define K_CODES 2048
#define DIM 256
#define NROWS 32768            // B*H*W
#define ROWS_PER_BLOCK 16
#define THREADS 512            // 8 waves
#define HW_STRIDE 1024         // H*W
#define ZQ_SIZE 8388608ULL     // 32*256*32*32
#define QLOSS_OFFSET 8388608
#define PROB_OFFSET 8388609ULL
#define ZB_PITCH 264           // ushorts per LDS z-row: 256 + 8 pad (16B) to break bank aliasing

typedef short v8s __attribute__((ext_vector_type(8)));   // 8 bf16 (guide-verified operand type)
typedef float v4f __attribute__((ext_vector_type(4)));

__device__ __forceinline__ ushort f2bf(float x) {
    uint32_t u = __float_as_uint(x);
    return (ushort)((u + 0x7FFFu + ((u >> 16) & 1u)) >> 16);   // RNE
}

// Prep: codebook fp32 -> bf16 (ws), cnorm[k] = sum c^2, zero the q_loss slot.
__global__ void prep_kernel(const float* __restrict__ cb, ushort* __restrict__ cbb,
                            float* __restrict__ cnorm, float* __restrict__ qloss) {
    const int code = blockIdx.x;
    const int lane = threadIdx.x;     // 64 threads
    float4 v = ((const float4*)(cb + code * DIM))[lane];
    ushort4 o;
    o.x = f2bf(v.x); o.y = f2bf(v.y); o.z = f2bf(v.z); o.w = f2bf(v.w);
    ((ushort4*)(cbb + code * DIM))[lane] = o;
    float ss = v.x * v.x + v.y * v.y + v.z * v.z + v.w * v.w;
    #pragma unroll
    for (int m = 32; m >= 1; m >>= 1) ss += __shfl_xor(ss, m, 64);
    if (lane == 0) cnorm[code] = ss;
    if (code == 0 && lane == 0) *qloss = 0.f;
}

__launch_bounds__(THREADS)
__global__ void vq_kernel(const float* __restrict__ z, const float* __restrict__ cb,
                          const ushort* __restrict__ cbb, const float* __restrict__ cnorm,
                          float* __restrict__ out) {
    __shared__ float zf[DIM * 16];                       // [d][m] fp32, 16 KB
    __shared__ ushort zb[ROWS_PER_BLOCK * ZB_PITCH];     // [m][k] bf16, padded
    __shared__ float red_sum[8][16];
    __shared__ float red_max[8][16];
    __shared__ float row_sum[16];
    __shared__ float row_max[16];
    __shared__ unsigned long long best[16];
    __shared__ int row_idx[16];
    __shared__ float lred[8];

    const int t = threadIdx.x;
    const int n0 = blockIdx.x * ROWS_PER_BLOCK;          // first global row
    const int bb = n0 >> 10;                             // batch index
    const int hw = n0 & 1023;                            // h*32 + w0 (16-aligned)
    const float* zbase = z + (size_t)bb * (DIM * HW_STRIDE) + hw;

    if (t < 16) best[t] = 0ULL;

    // ---- stage z -> zf [d][m] (coalesced float4: 4 consecutive w per d) ----
    #pragma unroll
    for (int j = 0; j < 2; ++j) {
        int i4 = t + j * THREADS;                        // 0..1023
        int d = i4 >> 2, m0 = (i4 & 3) << 2;
        float4 v = *(const float4*)(zbase + (size_t)d * HW_STRIDE + m0);
        *(float4*)&zf[d * 16 + m0] = v;
    }
    __syncthreads();
    // ---- transpose zf -> zb bf16 [m][k] for MFMA A-fragments ----
    #pragma unroll
    for (int j = 0; j < 4; ++j) {
        int i2 = t + j * THREADS;                        // 0..2047
        int m = i2 & 15, kp = i2 >> 4;                   // kp = k/2, 0..127
        float a0 = zf[(2 * kp) * 16 + m];
        float a1 = zf[(2 * kp + 1) * 16 + m];
        uint32_t pk = (uint32_t)f2bf(a0) | ((uint32_t)f2bf(a1) << 16);
        *(uint32_t*)&zb[m * ZB_PITCH + 2 * kp] = pk;
    }
    __syncthreads();

    const int wave = t >> 6, lane = t & 63;
    const int q = lane >> 4, lm = lane & 15;
    const int c0 = wave * 256;                           // this wave's code range

    // A fragments: lane holds A[m=lm][k = ks*32 + q*8 + j], all 8 k-steps (32 VGPRs)
    v8s afrag[8];
    const ushort* arow = &zb[lm * ZB_PITCH + q * 8];
    #pragma unroll
    for (int ks = 0; ks < 8; ++ks) afrag[ks] = *(const v8s*)(arow + ks * 32);

    // K-loop: 16 col-tiles x 8 k-steps; e[ct][r] ends as exp(logit)
    v4f e[16];
    float sume[4] = {0.f, 0.f, 0.f, 0.f};
    float emax[4] = {0.f, 0.f, 0.f, 0.f};
    #pragma unroll
    for (int ct = 0; ct < 16; ++ct) {
        const int code = c0 + ct * 16 + lm;
        const v8s* bp = (const v8s*)(cbb + code * DIM + q * 8);  // B[k][n=lm] = C[code][k]
        v4f a = {0.f, 0.f, 0.f, 0.f};
        #pragma unroll
        for (int ks = 0; ks < 8; ++ks)
            a = __builtin_amdgcn_mfma_f32_16x16x32_bf16(afrag[ks], bp[ks * 4], a, 0, 0, 0);
        const float cn = cnorm[code];
        #pragma unroll
        for (int r = 0; r < 4; ++r) {
            float ev = __expf(2.f * a[r] - cn);          // logit = 2 z.c - |c|^2  (|z|^2 cancels)
            a[r] = ev;
            sume[r] += ev;
            emax[r] = fmaxf(emax[r], ev);
        }
        e[ct] = a;
    }
    // butterfly across the 16 lanes of each quad (rows stay separated by quad)
    #pragma unroll
    for (int m = 1; m <= 8; m <<= 1) {
        #pragma unroll
        for (int r = 0; r < 4; ++r) {
            sume[r] += __shfl_xor(sume[r], m, 64);
            emax[r] = fmaxf(emax[r], __shfl_xor(emax[r], m, 64));
        }
    }
    if (lm == 0) {
        #pragma unroll
        for (int r = 0; r < 4; ++r) {
            red_sum[wave][q * 4 + r] = sume[r];
            red_max[wave][q * 4 + r] = emax[r];
        }
    }
    __syncthreads();
    if (t < 16) {
        float s = 0.f, mx = 0.f;
        #pragma unroll
        for (int w = 0; w < 8; ++w) { s += red_sum[w][t]; mx = fmaxf(mx, red_max[w][t]); }
        row_sum[t] = s;
        row_max[t] = mx;
    }
    __syncthreads();

    // ---- exact argmin: rescore candidates within 0.2% of row max (covers bf16 error),
    //      fp64 dot, packed atomicMax reproduces jnp.argmin first-index tie-break ----
    float thr[4];
    #pragma unroll
    for (int r = 0; r < 4; ++r) thr[r] = row_max[q * 4 + r] * 0.998f;
    unsigned long long cmask = 0ULL;
    #pragma unroll
    for (int ct = 0; ct < 16; ++ct) {
        #pragma unroll
        for (int r = 0; r < 4; ++r)
            if (e[ct][r] >= thr[r]) cmask |= 1ULL << (ct * 4 + r);
    }
    while (cmask) {
        int bit = __ffsll((unsigned long long)cmask) - 1;
        cmask &= cmask - 1;
        int ct = bit >> 2, r = bit & 3;
        int code = c0 + ct * 16 + lm;
        int row = q * 4 + r;
        const float4* crow = (const float4*)(cb + code * DIM);
        double dot = 0.0;
        for (int k4 = 0; k4 < 64; ++k4) {
            float4 cv = crow[k4];
            int kb = k4 * 4;
            dot += (double)zf[(kb) * 16 + row] * (double)cv.x;
            dot += (double)zf[(kb + 1) * 16 + row] * (double)cv.y;
            dot += (double)zf[(kb + 2) * 16 + row] * (double)cv.z;
            dot += (double)zf[(kb + 3) * 16 + row] * (double)cv.w;
        }
        float lg = (float)(2.0 * dot - (double)cnorm[code]);
        uint32_t u = __float_as_uint(lg);
        u = (u & 0x80000000u) ? ~u : (u | 0x80000000u);  // monotonic float->uint
        unsigned long long key =
            ((unsigned long long)u << 32) | (uint32_t)(0xFFFFFFFFu - (uint32_t)code);
        atomicMax(&best[row], key);
    }
    __syncthreads();
    if (t < 16) row_idx[t] = (int)(0xFFFFFFFFu - (uint32_t)(best[t] & 0xFFFFFFFFULL));
    __syncthreads();

    // ---- distance_prob writes (64B segments per quad-row, exactly once) ----
    float rinv[4];
    #pragma unroll
    for (int r = 0; r < 4; ++r) rinv[r] = 1.f / row_sum[q * 4 + r];
    float* prob = out + PROB_OFFSET;
    #pragma unroll
    for (int ct = 0; ct < 16; ++ct) {
        int col = c0 + ct * 16 + lm;
        #pragma unroll
        for (int r = 0; r < 4; ++r)
            prob[(size_t)(n0 + q * 4 + r) * K_CODES + col] = e[ct][r] * rinv[r];
    }

    // ---- z_q output (gather codebook rows, scatter back to (b,d,h,w)) + q_loss ----
    float lacc = 0.f;
    #pragma unroll
    for (int j = 0; j < 2; ++j) {
        int i4 = t + j * THREADS;
        int d = i4 >> 2, m0 = (i4 & 3) << 2;
        float ov[4];
        #pragma unroll
        for (int i = 0; i < 4; ++i) {
            int m = m0 + i;
            float cv = cb[row_idx[m] * DIM + d];
            float zv = zf[d * 16 + m];
            float df = zv - cv;
            lacc += df * df;
            ov[i] = cv;
        }
        *(float4*)(out + (size_t)bb * (DIM * HW_STRIDE) + hw + (size_t)d * HW_STRIDE + m0) =
            make_float4(ov[0], ov[1], ov[2], ov[3]);
    }
    #pragma unroll
    for (int m = 32; m >= 1; m >>= 1) lacc += __shfl_xor(lacc, m, 64);
    if (lane == 0) lred[wave] = lacc;
    __syncthreads();
    if (t == 0) {
        float s = 0.f;
        #pragma unroll
        for (int w = 0; w < 8; ++w) s += lred[w];
        // q_loss = (1 + BETA) * mean((z_q - z)^2), forward values of both losses coincide
        atomicAdd(out + QLOSS_OFFSET, s * (1.25f / 8388608.f));
    }
}

extern "C" void kernel_launch(void* const* d_in, const int* in_sizes, int n_in,
                              void* d_out, int out_size, void* d_ws, size_t ws_size,
                              hipStream_t stream) {
    const float* z  = (const float*)d_in[0];   // (32,256,32,32) fp32
    const float* cb = (const float*)d_in[1];   // (2048,256) fp32
    float* out = (float*)d_out;
    ushort* cbb  = (ushort*)d_ws;                                  // bf16 codebook, 1 MB
    float*  cnm  = (float*)((char*)d_ws + (size_t)K_CODES * DIM * sizeof(ushort));
    prep_kernel<<<K_CODES, 64, 0, stream>>>(cb, cbb, cnm, out + QLOSS_OFFSET);
    vq_kernel<<<NROWS / ROWS_PER_BLOCK, THREADS, 0, stream>>>(z, cb, cbb, cnm, out);
}

// Round 3
// 604.167 us; speedup vs baseline: 1.1438x; 1.1438x over previous
//
#include <hip/hip_runtime.h>
#include <hip/hip_bf16.h>
#include <stdint.h>

// Problem constants (B=32, D=256, H=32, W=32, K=2048)
#define K_CODES 2048
#define DIM 256
#define NROWS 32768            // B*H*W
#define ROWS_PER_BLOCK 16
#define THREADS 512            // 8 waves
#define HW_STRIDE 1024         // H*W
#define QLOSS_OFFSET 8388608
#define PROB_OFFSET 8388609ULL
#define ZB_PITCH 264           // ushorts per LDS z-row: 256 + 8 pad

typedef short v8s __attribute__((ext_vector_type(8)));   // 8 bf16 (MFMA operand)
typedef float v4f __attribute__((ext_vector_type(4)));
typedef __fp16 v2h __attribute__((ext_vector_type(2))); // matches cvt_pkrtz return type

__device__ __forceinline__ ushort f2bf(float x) {
    uint32_t u = __float_as_uint(x);
    return (ushort)((u + 0x7FFFu + ((u >> 16) & 1u)) >> 16);   // RNE
}

// Prep: codebook fp32 -> bf16 (ws), cnorm[k] = sum c^2, zero the q_loss slot.
__global__ void prep_kernel(const float* __restrict__ cb, ushort* __restrict__ cbb,
                            float* __restrict__ cnorm, float* __restrict__ qloss) {
    const int code = blockIdx.x;
    const int lane = threadIdx.x;     // 64 threads
    float4 v = ((const float4*)(cb + code * DIM))[lane];
    ushort4 o;
    o.x = f2bf(v.x); o.y = f2bf(v.y); o.z = f2bf(v.z); o.w = f2bf(v.w);
    ((ushort4*)(cbb + code * DIM))[lane] = o;
    float ss = v.x * v.x + v.y * v.y + v.z * v.z + v.w * v.w;
    #pragma unroll
    for (int m = 32; m >= 1; m >>= 1) ss += __shfl_xor(ss, m, 64);
    if (lane == 0) cnorm[code] = ss;
    if (code == 0 && lane == 0) *qloss = 0.f;
}

// cap at 128 VGPR (4 waves/EU) so two 8-wave blocks co-reside per CU
__launch_bounds__(THREADS, 4)
__global__ void vq_kernel(const float* __restrict__ z, const float* __restrict__ cb,
                          const ushort* __restrict__ cbb, const float* __restrict__ cnorm,
                          float* __restrict__ out) {
    __shared__ float zf[DIM * 16];                       // [d][m] fp32, 16 KB
    __shared__ ushort zb[ROWS_PER_BLOCK * ZB_PITCH];     // [m][k] bf16, padded
    __shared__ float red_sum[8][16];
    __shared__ float red_val[8][16];
    __shared__ int   red_code[8][16];
    __shared__ float row_sum[16];
    __shared__ int   row_idx[16];
    __shared__ float lred[8];

    const int t = threadIdx.x;
    const int n0 = blockIdx.x * ROWS_PER_BLOCK;          // first global row
    const int bb = n0 >> 10;                             // batch index
    const int hw = n0 & 1023;                            // h*32 + w0 (16-aligned)
    const float* zbase = z + (size_t)bb * (DIM * HW_STRIDE) + hw;

    // ---- stage z -> zf [d][m] (coalesced float4: 4 consecutive w per d) ----
    #pragma unroll
    for (int j = 0; j < 2; ++j) {
        int i4 = t + j * THREADS;                        // 0..1023
        int d = i4 >> 2, m0 = (i4 & 3) << 2;
        float4 v = *(const float4*)(zbase + (size_t)d * HW_STRIDE + m0);
        *(float4*)&zf[d * 16 + m0] = v;
    }
    __syncthreads();
    // ---- transpose zf -> zb bf16 [m][k] for MFMA A-fragments ----
    #pragma unroll
    for (int j = 0; j < 4; ++j) {
        int i2 = t + j * THREADS;                        // 0..2047
        int m = i2 & 15, kp = i2 >> 4;                   // kp = k/2, 0..127
        float a0 = zf[(2 * kp) * 16 + m];
        float a1 = zf[(2 * kp + 1) * 16 + m];
        uint32_t pk = (uint32_t)f2bf(a0) | ((uint32_t)f2bf(a1) << 16);
        *(uint32_t*)&zb[m * ZB_PITCH + 2 * kp] = pk;
    }
    __syncthreads();

    const int wave = t >> 6, lane = t & 63;
    const int q = lane >> 4, lm = lane & 15;
    const int c0 = wave * 256;                           // this wave's code range

    // A fragments: lane holds A[m=lm][k = ks*32 + q*8 + j], all 8 k-steps (32 VGPRs)
    v8s afrag[8];
    const ushort* arow = &zb[lm * ZB_PITCH + q * 8];
    #pragma unroll
    for (int ks = 0; ks < 8; ++ks) afrag[ks] = *(const v8s*)(arow + ks * 32);

    // K-loop: 16 col-tiles x 8 k-steps. exp values packed to fp16 pairs (32 regs),
    // row-sum in fp32, argmax-of-logit tracked in registers (strict > == first-index
    // tie-break within a lane since code increases with ct).
    v2h ep[32];
    float sume[4] = {0.f, 0.f, 0.f, 0.f};
    float bval[4] = {-1e30f, -1e30f, -1e30f, -1e30f};
    int   bcode[4] = {0, 0, 0, 0};
    #pragma unroll
    for (int ct = 0; ct < 16; ++ct) {
        const int code = c0 + ct * 16 + lm;
        const v8s* bp = (const v8s*)(cbb + code * DIM + q * 8);  // B[k][n=lm] = C[code][k]
        v4f a = {0.f, 0.f, 0.f, 0.f};
        #pragma unroll
        for (int ks = 0; ks < 8; ++ks)
            a = __builtin_amdgcn_mfma_f32_16x16x32_bf16(afrag[ks], bp[ks * 4], a, 0, 0, 0);
        const float cn = cnorm[code];
        #pragma unroll
        for (int r = 0; r < 4; ++r) {
            float l = 2.f * a[r] - cn;                   // logit = 2 z.c - |c|^2 (|z|^2 cancels)
            float ev = __expf(l);
            sume[r] += ev;
            if (l > bval[r]) { bval[r] = l; bcode[r] = code; }
            a[r] = ev;
        }
        ep[2 * ct]     = __builtin_amdgcn_cvt_pkrtz(a[0], a[1]);
        ep[2 * ct + 1] = __builtin_amdgcn_cvt_pkrtz(a[2], a[3]);
    }
    // butterfly across the 16 lanes (lm) of each quad-row group
    #pragma unroll
    for (int m = 1; m <= 8; m <<= 1) {
        #pragma unroll
        for (int r = 0; r < 4; ++r) {
            sume[r] += __shfl_xor(sume[r], m, 64);
            float v2 = __shfl_xor(bval[r], m, 64);
            int   c2 = __shfl_xor(bcode[r], m, 64);
            if (v2 > bval[r] || (v2 == bval[r] && c2 < bcode[r])) { bval[r] = v2; bcode[r] = c2; }
        }
    }
    if (lm == 0) {
        #pragma unroll
        for (int r = 0; r < 4; ++r) {
            red_sum[wave][q * 4 + r]  = sume[r];
            red_val[wave][q * 4 + r]  = bval[r];
            red_code[wave][q * 4 + r] = bcode[r];
        }
    }
    __syncthreads();
    if (t < 16) {
        float s = 0.f, bv = -1e30f;
        int bc = 0;
        #pragma unroll
        for (int w = 0; w < 8; ++w) {
            s += red_sum[w][t];
            float v = red_val[w][t];
            int   c = red_code[w][t];
            if (v > bv || (v == bv && c < bc)) { bv = v; bc = c; }
        }
        row_sum[t] = s;
        row_idx[t] = bc;
    }
    __syncthreads();

    // ---- distance_prob writes (full 64B lines per quad-row, exactly once) ----
    float rinv[4];
    #pragma unroll
    for (int r = 0; r < 4; ++r) rinv[r] = 1.f / row_sum[q * 4 + r];
    float* prob = out + PROB_OFFSET;
    #pragma unroll
    for (int ct = 0; ct < 16; ++ct) {
        int col = c0 + ct * 16 + lm;
        float e0 = (float)ep[2 * ct][0];
        float e1 = (float)ep[2 * ct][1];
        float e2 = (float)ep[2 * ct + 1][0];
        float e3 = (float)ep[2 * ct + 1][1];
        size_t base = (size_t)(n0 + q * 4) * K_CODES + col;
        prob[base]                = e0 * rinv[0];
        prob[base + K_CODES]      = e1 * rinv[1];
        prob[base + 2 * K_CODES]  = e2 * rinv[2];
        prob[base + 3 * K_CODES]  = e3 * rinv[3];
    }

    // ---- z_q output (gather codebook rows, scatter back to (b,d,h,w)) + q_loss ----
    float lacc = 0.f;
    #pragma unroll
    for (int j = 0; j < 2; ++j) {
        int i4 = t + j * THREADS;
        int d = i4 >> 2, m0 = (i4 & 3) << 2;
        float ov[4];
        #pragma unroll
        for (int i = 0; i < 4; ++i) {
            int m = m0 + i;
            float cv = cb[row_idx[m] * DIM + d];
            float zv = zf[d * 16 + m];
            float df = zv - cv;
            lacc += df * df;
            ov[i] = cv;
        }
        *(float4*)(out + (size_t)bb * (DIM * HW_STRIDE) + hw + (size_t)d * HW_STRIDE + m0) =
            make_float4(ov[0], ov[1], ov[2], ov[3]);
    }
    #pragma unroll
    for (int m = 32; m >= 1; m >>= 1) lacc += __shfl_xor(lacc, m, 64);
    if (lane == 0) lred[wave] = lacc;
    __syncthreads();
    if (t == 0) {
        float s = 0.f;
        #pragma unroll
        for (int w = 0; w < 8; ++w) s += lred[w];
        // q_loss = (1 + BETA) * mean((z_q - z)^2); both loss terms coincide in fwd
        atomicAdd(out + QLOSS_OFFSET, s * (1.25f / 8388608.f));
    }
}

extern "C" void kernel_launch(void* const* d_in, const int* in_sizes, int n_in,
                              void* d_out, int out_size, void* d_ws, size_t ws_size,
                              hipStream_t stream) {
    const float* z  = (const float*)d_in[0];   // (32,256,32,32) fp32
    const float* cb = (const float*)d_in[1];   // (2048,256) fp32
    float* out = (float*)d_out;
    ushort* cbb  = (ushort*)d_ws;                                  // bf16 codebook, 1 MB
    float*  cnm  = (float*)((char*)d_ws + (size_t)K_CODES * DIM * sizeof(ushort));
    prep_kernel<<<K_CODES, 64, 0, stream>>>(cb, cbb, cnm, out + QLOSS_OFFSET);
    vq_kernel<<<NROWS / ROWS_PER_BLOCK, THREADS, 0, stream>>>(z, cb, cbb, cnm, out);
}